// Round 8
// baseline (638.652 us; speedup 1.0000x reference)
//
#include <hip/hip_runtime.h>
#include <cmath>
#include <cstdint>

#define LN_EPS 1e-5f

typedef __bf16 bf16x8 __attribute__((ext_vector_type(8)));
typedef float f32x4 __attribute__((ext_vector_type(4)));
typedef unsigned short u16x8 __attribute__((ext_vector_type(8)));
typedef unsigned short u16x4 __attribute__((ext_vector_type(4)));

__device__ inline float b2f(unsigned short u) {
    union { unsigned int ui; float f; } x; x.ui = ((unsigned int)u) << 16; return x.f;
}
__device__ inline unsigned short f2b(float f) {
    union { float f; unsigned int ui; } x; x.f = f;
    unsigned int u = x.ui;
    return (unsigned short)((u + 0x7FFFu + ((u >> 16) & 1u)) >> 16);  // RNE
}

// ---------------- fused fp32 -> bf16 convert of two arrays ----------------
__global__ void cvt2_kernel(const float* __restrict__ ia, unsigned short* __restrict__ oa,
                            long na, float sa,
                            const float* __restrict__ ib, unsigned short* __restrict__ ob,
                            long nb) {
    long i = ((long)blockIdx.x * blockDim.x + threadIdx.x) * 8;
    long stride = (long)gridDim.x * blockDim.x * 8;
    long n = na + nb;
    for (; i < n; i += stride) {
        const float* in; unsigned short* out; long j; float s;
        if (i < na) { in = ia; out = oa; j = i; s = sa; }
        else        { in = ib; out = ob; j = i - na; s = 1.0f; }
        float4 a = *reinterpret_cast<const float4*>(in + j);
        float4 b = *reinterpret_cast<const float4*>(in + j + 4);
        u16x8 o;
        o[0] = f2b(a.x * s); o[1] = f2b(a.y * s); o[2] = f2b(a.z * s); o[3] = f2b(a.w * s);
        o[4] = f2b(b.x * s); o[5] = f2b(b.y * s); o[6] = f2b(b.z * s); o[7] = f2b(b.w * s);
        *reinterpret_cast<u16x8*>(out + j) = o;
    }
}

// ---------------- V (B,S,D) fp32 -> Vt (B,D,S) bf16 ----------------
__global__ void transpose_kernel(const float* __restrict__ V, unsigned short* __restrict__ Vt,
                                 int S, int D) {
    __shared__ float t[32][33];
    int b = blockIdx.z;
    int s0 = blockIdx.x * 32, d0 = blockIdx.y * 32;
    int tx = threadIdx.x & 31, ty = threadIdx.x >> 5;
    const float* Vb = V + (long)b * S * D;
    unsigned short* Vtb = Vt + (long)b * S * D;
#pragma unroll
    for (int r = 0; r < 4; ++r)
        t[ty + r * 8][tx] = Vb[(long)(s0 + ty + r * 8) * D + d0 + tx];
    __syncthreads();
#pragma unroll
    for (int r = 0; r < 4; ++r)
        Vtb[(long)(d0 + ty + r * 8) * S + s0 + tx] = f2b(t[tx][ty + r * 8]);
}

// ====== persistent 256x256 8-wave phased NT GEMM (R5 body, TPB tiles/block) ======
// MODE 0: QK^T: p=exp(s) bf16 unnormalized; partial row sums -> aux1[(bz*tX+bx)*2048+row]
// MODE 1: X = acc*invL[row] + b2f(Qb[idx])*scale, bf16; invL computed in prologue from
//         aux2 (stats); LN1 (sum,sumsq) partials -> aux3/aux4
// MODE 2: H = bf16(relu(acc + aux1[n]))                   (aux1 = b1)
// MODE 3: Y = bf16(acc + aux1[n] + b2f(aux2_bf16[idx]))   (aux1 = b2, aux2 = Xb)
#define GBK 64

__device__ inline void gload16(const unsigned short* g, unsigned short* l) {
    __builtin_amdgcn_global_load_lds((const __attribute__((address_space(1))) void*)g,
                                     (__attribute__((address_space(3))) void*)l, 16, 0, 0);
}

__device__ inline void stage_half(const unsigned short* gRowBase, int ldk, int k0,
                                  unsigned short* ldsHalf, int tid) {
#pragma unroll
    for (int l = 0; l < 2; ++l) {
        int g = l * 512 + tid;
        int row = g >> 3;
        int lg = (g & 7) ^ (row & 7);
        gload16(gRowBase + (long)row * ldk + k0 + lg * 8, ldsHalf + g * 8);
    }
}

__device__ inline bf16x8 frag_ld(const unsigned short* ldsHalf, int rowInHalf, int kgran) {
    int sw = kgran ^ (rowInHalf & 7);
    return *reinterpret_cast<const bf16x8*>(ldsHalf + rowInHalf * 64 + sw * 8);
}

#define GMFMA(am, bn, mi, ni) \
    acc[mi][ni] = __builtin_amdgcn_mfma_f32_16x16x32_bf16(am, bn, acc[mi][ni], 0, 0, 0)

template <int MODE>
__global__ __launch_bounds__(512, 1) void gemm256(
    const unsigned short* __restrict__ A, const unsigned short* __restrict__ B,
    void* __restrict__ Cout, const float* __restrict__ aux1, const float* __restrict__ aux2,
    float* __restrict__ aux3, float* __restrict__ aux4,
    int tX, int tY, int N, int K, long bsA, long bsB, long bsC, float scale, int TPB) {
    extern __shared__ __align__(16) unsigned short lds[];
    // chunked XCD swizzle on BLOCK index; block owns TPB consecutive tiles (same A panel)
    const int cpx = gridDim.x >> 3;
    const int swz = (blockIdx.x & 7) * cpx + (blockIdx.x >> 3);
    const int t0 = swz * TPB;
    const int bx0 = t0 % tX;
    const int byz = t0 / tX;
    const int by = byz % tY, bz = byz / tY;

    const unsigned short* Ab = A + (long)bz * bsA + (long)by * 256 * K;
    const unsigned short* BbC = B + (long)bz * bsB + (long)bx0 * 256 * K;
    const unsigned short* BbN = BbC + (TPB > 1 ? (long)256 * K : 0);

    const int tid = threadIdx.x;
    const int wid = tid >> 6, lane = tid & 63;
    const int wr = wid >> 2, wc = wid & 3;
    const int lr = lane & 15, kq = lane >> 4;
    const int NT = K >> 6;
    const int TOT = TPB * NT;
    const int ccol = lane & 15, crow0 = kq * 4;
    const long m0 = (long)by * 256 + wr * 128;
    const int bRow0 = (wc & 1) * 64;

#define SA0(kt, dst) stage_half(Ab, K, (kt) * GBK, dst, tid)
#define SA1(kt, dst) stage_half(Ab + (long)128 * K, K, (kt) * GBK, dst, tid)
#define SB0(base, kt, dst) stage_half(base, K, (kt) * GBK, dst, tid)
#define SB1(base, kt, dst) stage_half(base + (long)128 * K, K, (kt) * GBK, dst, tid)

    f32x4 acc[8][4];
#pragma unroll
    for (int i = 0; i < 8; ++i)
#pragma unroll
        for (int j = 0; j < 4; ++j) acc[i][j] = (f32x4){0.f, 0.f, 0.f, 0.f};
    bf16x8 a[4][2], b[4][2];

    // MODE1: per-row 1/L into LDS scratch (loads issued before staging -> FIFO keeps
    // the auto-waitcnt for these from draining the staging queue)
    if (MODE == 1) {
        float* invLl = (float*)(lds + 69632);
        if (tid < 256) {
            int row = by * 256 + tid;
            float L = 0.f;
#pragma unroll
            for (int x = 0; x < 8; ++x) L += aux2[((long)bz * 8 + x) * 2048 + row];
            invLl[tid] = 1.f / L;
        }
    }

    // prologue: tile0 k=0 all halves + k=1 h0 halves
    SA0(0, lds);            SA1(0, lds + 8192);
    SB0(BbC, 0, lds + 16384); SB1(BbC, 0, lds + 24576);
    SB0(BbC, 1, lds + 32768 + 16384);
    SA0(1, lds + 32768);
    asm volatile("s_waitcnt vmcnt(4) lgkmcnt(0)" ::: "memory");
    __builtin_amdgcn_s_barrier();

    int k = 0, ti = 0;
    for (int ft = 0; ft < TOT; ++ft) {
        const unsigned short* aB = lds + ((ft & 1) * 32768 + wr * 8192);
        const unsigned short* bB = lds + ((ft & 1) * 32768 + 16384 + (wc >> 1) * 8192);
        unsigned short* buf1 = lds + ((ft + 1) & 1) * 32768;
        unsigned short* buf2 = lds + (ft & 1) * 32768;
        const bool s1 = (ft + 1 < TOT), s2 = (ft + 2 < TOT);
        const bool in1 = (k + 1 < NT), in2 = (k + 2 < NT);
        const int k1 = in1 ? k + 1 : 0;
        const int k2 = in2 ? k + 2 : k + 2 - NT;
        const unsigned short* B1 = in1 ? BbC : BbN;
        const unsigned short* B2 = in2 ? BbC : BbN;

        // ---- P1 ----
#pragma unroll
        for (int m = 0; m < 4; ++m)
#pragma unroll
            for (int ks = 0; ks < 2; ++ks)
                a[m][ks] = frag_ld(aB, m * 16 + lr, ks * 4 + kq);
#pragma unroll
        for (int n = 0; n < 2; ++n)
#pragma unroll
            for (int ks = 0; ks < 2; ++ks)
                b[n][ks] = frag_ld(bB, bRow0 + n * 16 + lr, ks * 4 + kq);
        if (s1) SA1(k1, buf1 + 8192);
        __builtin_amdgcn_s_barrier();
        asm volatile("s_waitcnt lgkmcnt(0)" ::: "memory");
        __builtin_amdgcn_sched_barrier(0);
        __builtin_amdgcn_s_setprio(1);
#pragma unroll
        for (int m = 0; m < 4; ++m)
#pragma unroll
            for (int n = 0; n < 2; ++n)
#pragma unroll
                for (int ks = 0; ks < 2; ++ks) GMFMA(a[m][ks], b[n][ks], m, n);
        __builtin_amdgcn_s_setprio(0);
        __builtin_amdgcn_s_barrier();
        // ---- P2 ----
#pragma unroll
        for (int n = 0; n < 2; ++n)
#pragma unroll
            for (int ks = 0; ks < 2; ++ks)
                b[2 + n][ks] = frag_ld(bB, bRow0 + (2 + n) * 16 + lr, ks * 4 + kq);
        if (s1) SB1(B1, k1, buf1 + 24576);
        __builtin_amdgcn_s_barrier();
        asm volatile("s_waitcnt lgkmcnt(0)" ::: "memory");
        __builtin_amdgcn_sched_barrier(0);
        __builtin_amdgcn_s_setprio(1);
#pragma unroll
        for (int m = 0; m < 4; ++m)
#pragma unroll
            for (int n = 0; n < 2; ++n)
#pragma unroll
                for (int ks = 0; ks < 2; ++ks) GMFMA(a[m][ks], b[2 + n][ks], m, 2 + n);
        __builtin_amdgcn_s_setprio(0);
        __builtin_amdgcn_s_barrier();
        // ---- P3 ----
#pragma unroll
        for (int m = 0; m < 4; ++m)
#pragma unroll
            for (int ks = 0; ks < 2; ++ks)
                a[m][ks] = frag_ld(aB, 64 + m * 16 + lr, ks * 4 + kq);
        if (s2) SB0(B2, k2, buf2 + 16384);
        __builtin_amdgcn_s_barrier();
        asm volatile("s_waitcnt lgkmcnt(0)" ::: "memory");
        __builtin_amdgcn_sched_barrier(0);
        __builtin_amdgcn_s_setprio(1);
#pragma unroll
        for (int m = 0; m < 4; ++m)
#pragma unroll
            for (int n = 0; n < 2; ++n)
#pragma unroll
                for (int ks = 0; ks < 2; ++ks) GMFMA(a[m][ks], b[n][ks], 4 + m, n);
        __builtin_amdgcn_s_setprio(0);
        __builtin_amdgcn_s_barrier();
        // ---- P4 ----
        if (s2) SA0(k2, buf2);
        if (ft < TOT - 2) asm volatile("s_waitcnt vmcnt(4)" ::: "memory");
        else              asm volatile("s_waitcnt vmcnt(0)" ::: "memory");
        __builtin_amdgcn_s_barrier();
        __builtin_amdgcn_s_setprio(1);
#pragma unroll
        for (int m = 0; m < 4; ++m)
#pragma unroll
            for (int n = 0; n < 2; ++n)
#pragma unroll
                for (int ks = 0; ks < 2; ++ks) GMFMA(a[m][ks], b[2 + n][ks], 4 + m, 2 + n);
        __builtin_amdgcn_s_setprio(0);
        __builtin_amdgcn_s_barrier();

        // ---- tile boundary: epilogue (scratch beyond 128 KiB; staged bufs untouched) ----
        if (k == NT - 1) {
            const int bx = bx0 + ti;
            const long n0 = (long)bx * 256 + wc * 64;
            if (MODE == 0) {
                float* sl = (float*)(lds + 65536);  // 4 KB scratch @131072B
                unsigned short* Pout = (unsigned short*)Cout;
#pragma unroll
                for (int m = 0; m < 8; ++m) {
                    float ls[4] = {0.f, 0.f, 0.f, 0.f};
#pragma unroll
                    for (int n = 0; n < 4; ++n) {
                        long gn = n0 + n * 16 + ccol;
#pragma unroll
                        for (int r = 0; r < 4; ++r) {
                            float p = __expf(acc[m][n][r]);
                            ls[r] += p;
                            Pout[bz * bsC + (m0 + m * 16 + crow0 + r) * N + gn] = f2b(p);
                        }
                    }
#pragma unroll
                    for (int r = 0; r < 4; ++r)
#pragma unroll
                        for (int off = 8; off >= 1; off >>= 1) ls[r] += __shfl_xor(ls[r], off, 64);
                    if ((lane & 15) == 0)
#pragma unroll
                        for (int r = 0; r < 4; ++r)
                            sl[wc * 256 + wr * 128 + m * 16 + crow0 + r] = ls[r];
                }
                __syncthreads();
                if (wc == 0) {
#pragma unroll
                    for (int rep = 0; rep < 2; ++rep) {
                        int rowB = wr * 128 + rep * 64 + lane;
                        float s4 = sl[0 * 256 + rowB] + sl[1 * 256 + rowB] +
                                   sl[2 * 256 + rowB] + sl[3 * 256 + rowB];
                        ((float*)aux1)[((long)bz * tX + bx) * 2048 + by * 256 + rowB] = s4;
                    }
                }
            } else if (MODE == 1) {
                const float* invLl = (const float*)(lds + 69632);
                float* sls = (float*)(lds + 65536);
                float* slq = sls + 1024;
                unsigned short* Xout = (unsigned short*)Cout;
#pragma unroll
                for (int m = 0; m < 8; ++m) {
                    float ls[4] = {0.f, 0.f, 0.f, 0.f}, lq[4] = {0.f, 0.f, 0.f, 0.f};
#pragma unroll
                    for (int r = 0; r < 4; ++r) {
                        float cf = invLl[wr * 128 + m * 16 + crow0 + r];
                        long gm = m0 + m * 16 + crow0 + r;
#pragma unroll
                        for (int n = 0; n < 4; ++n) {
                            long gn = n0 + n * 16 + ccol;
                            long idx = bz * bsC + gm * N + gn;
                            float v = acc[m][n][r] * cf +
                                      b2f(((const unsigned short*)aux1)[idx]) * scale;
                            Xout[idx] = f2b(v);
                            ls[r] += v; lq[r] += v * v;
                        }
                    }
#pragma unroll
                    for (int r = 0; r < 4; ++r)
#pragma unroll
                        for (int off = 8; off >= 1; off >>= 1) {
                            ls[r] += __shfl_xor(ls[r], off, 64);
                            lq[r] += __shfl_xor(lq[r], off, 64);
                        }
                    if ((lane & 15) == 0)
#pragma unroll
                        for (int r = 0; r < 4; ++r) {
                            sls[wc * 256 + wr * 128 + m * 16 + crow0 + r] = ls[r];
                            slq[wc * 256 + wr * 128 + m * 16 + crow0 + r] = lq[r];
                        }
                }
                __syncthreads();
                if (wc == 0) {
#pragma unroll
                    for (int rep = 0; rep < 2; ++rep) {
                        int rowB = wr * 128 + rep * 64 + lane;
                        float s4 = sls[rowB] + sls[256 + rowB] + sls[512 + rowB] + sls[768 + rowB];
                        float q4 = slq[rowB] + slq[256 + rowB] + slq[512 + rowB] + slq[768 + rowB];
                        long sidx = ((long)bz * tX + bx) * 2048 + by * 256 + rowB;
                        aux3[sidx] = s4;
                        aux4[sidx] = q4;
                    }
                }
            } else {
#pragma unroll
                for (int m = 0; m < 8; ++m) {
#pragma unroll
                    for (int n = 0; n < 4; ++n) {
                        long gn = n0 + n * 16 + ccol;
#pragma unroll
                        for (int r = 0; r < 4; ++r) {
                            long gm = m0 + m * 16 + crow0 + r;
                            float v = acc[m][n][r];
                            if (MODE == 2) {
                                ((unsigned short*)Cout)[gm * N + gn] =
                                    f2b(fmaxf(v + aux1[gn], 0.f));
                            } else {
                                long idx = gm * N + gn;
                                ((unsigned short*)Cout)[idx] =
                                    f2b(v + aux1[gn] + b2f(((const unsigned short*)aux2)[idx]));
                            }
                        }
                    }
                }
            }
#pragma unroll
            for (int i = 0; i < 8; ++i)
#pragma unroll
                for (int j = 0; j < 4; ++j) acc[i][j] = (f32x4){0.f, 0.f, 0.f, 0.f};
            ++ti;
            BbC = BbN;
            if (ti + 1 < TPB) BbN += (long)256 * K;
            k = 0;
        } else {
            ++k;
        }
    }
#undef SA0
#undef SA1
#undef SB0
#undef SB1
}

// ---------------- LN1 apply with inline stats combine (bf16 in-place) ----------------
__global__ void ln_apply_kernel(unsigned short* __restrict__ X, const float* __restrict__ ss,
                                const float* __restrict__ sq, const float* __restrict__ gamma,
                                const float* __restrict__ beta) {
    __shared__ float mr[4];
    int tid = threadIdx.x;
    long rowbase = (long)blockIdx.x * 2;  // 2 rows / block
    if (tid < 2) {
        long row = rowbase + tid;
        int bz = (int)(row >> 11), lrow = (int)(row & 2047);
        long base = (long)bz * 4 * 2048 + lrow;
        float s = 0.f, q = 0.f;
#pragma unroll
        for (int t = 0; t < 4; ++t) { s += ss[base + t * 2048]; q += sq[base + t * 2048]; }
        float m = s * (1.f / 1024.f);
        float var = q * (1.f / 1024.f) - m * m;
        mr[tid * 2] = m;
        mr[tid * 2 + 1] = rsqrtf(var + LN_EPS);
    }
    __syncthreads();
    int sub = tid >> 7;
    float m = mr[sub * 2], r = mr[sub * 2 + 1];
    long i = rowbase * 1024 + (long)tid * 8;
    int col = (tid * 8) & 1023;
    u16x8 raw = *reinterpret_cast<const u16x8*>(X + i);
    float4 g0 = *reinterpret_cast<const float4*>(gamma + col);
    float4 g1 = *reinterpret_cast<const float4*>(gamma + col + 4);
    float4 b0 = *reinterpret_cast<const float4*>(beta + col);
    float4 b1 = *reinterpret_cast<const float4*>(beta + col + 4);
    u16x8 o;
    o[0] = f2b((b2f(raw[0]) - m) * r * g0.x + b0.x);
    o[1] = f2b((b2f(raw[1]) - m) * r * g0.y + b0.y);
    o[2] = f2b((b2f(raw[2]) - m) * r * g0.z + b0.z);
    o[3] = f2b((b2f(raw[3]) - m) * r * g0.w + b0.w);
    o[4] = f2b((b2f(raw[4]) - m) * r * g1.x + b1.x);
    o[5] = f2b((b2f(raw[5]) - m) * r * g1.y + b1.y);
    o[6] = f2b((b2f(raw[6]) - m) * r * g1.z + b1.z);
    o[7] = f2b((b2f(raw[7]) - m) * r * g1.w + b1.w);
    *reinterpret_cast<u16x8*>(X + i) = o;
}

// ---------------- final LayerNorm: bf16 rows in, fp32 out ----------------
__device__ inline float wave_sum(float v) {
#pragma unroll
    for (int off = 32; off > 0; off >>= 1) v += __shfl_xor(v, off, 64);
    return v;
}

__global__ void ln_final_kernel(const unsigned short* __restrict__ Yb,
                                const float* __restrict__ gamma, const float* __restrict__ beta,
                                float* __restrict__ out) {
    __shared__ float red[8];
    long row = blockIdx.x;
    const unsigned short* y = Yb + row * 1024;
    int tid = threadIdx.x;
    int wv = tid >> 6, ln = tid & 63;
    u16x4 raw = *reinterpret_cast<const u16x4*>(y + tid * 4);
    float v0 = b2f(raw[0]), v1 = b2f(raw[1]), v2 = b2f(raw[2]), v3 = b2f(raw[3]);
    float s = v0 + v1 + v2 + v3;
    float q = v0 * v0 + v1 * v1 + v2 * v2 + v3 * v3;
    s = wave_sum(s);
    q = wave_sum(q);
    if (ln == 0) { red[wv] = s; red[4 + wv] = q; }
    __syncthreads();
    s = red[0] + red[1] + red[2] + red[3];
    q = red[4] + red[5] + red[6] + red[7];
    float mu = s * (1.f / 1024.f);
    float var = q * (1.f / 1024.f) - mu * mu;
    float rsg = rsqrtf(var + LN_EPS);
    float4 g = *reinterpret_cast<const float4*>(gamma + tid * 4);
    float4 b = *reinterpret_cast<const float4*>(beta + tid * 4);
    float4 o;
    o.x = (v0 - mu) * rsg * g.x + b.x;
    o.y = (v1 - mu) * rsg * g.y + b.y;
    o.z = (v2 - mu) * rsg * g.z + b.z;
    o.w = (v3 - mu) * rsg * g.w + b.w;
    *reinterpret_cast<float4*>(out + row * 1024 + tid * 4) = o;
}

extern "C" void kernel_launch(void* const* d_in, const int* in_sizes, int n_in,
                              void* d_out, int out_size, void* d_ws, size_t ws_size,
                              hipStream_t stream) {
    const float* Q     = (const float*)d_in[0];
    const float* Kin   = (const float*)d_in[1];
    const float* V     = (const float*)d_in[2];
    const float* W1    = (const float*)d_in[3];
    const float* b1    = (const float*)d_in[4];
    const float* W2    = (const float*)d_in[5];
    const float* b2    = (const float*)d_in[6];
    const float* gamma = (const float*)d_in[7];
    const float* beta  = (const float*)d_in[8];
    float* out = (float*)d_out;

    const int Bq = 16, S = 2048, D = 1024;
    const long SD = (long)S * D;
    const long SS = (long)S * S;
    const long rows = (long)Bq * S;  // 32768

    const size_t NEED = 3 * (size_t)(Bq * SD * 2) + 2 * (size_t)D * D * 2 + (size_t)(Bq * SS * 2);
    if (ws_size < NEED) return;

    char* ws = (char*)d_ws;
    unsigned short* Qb  = (unsigned short*)ws; ws += Bq * SD * 2;
    unsigned short* Kb  = (unsigned short*)ws; ws += Bq * SD * 2;
    unsigned short* Vt  = (unsigned short*)ws; ws += Bq * SD * 2;
    unsigned short* W1b = (unsigned short*)ws; ws += (long)D * D * 2;
    unsigned short* W2b = (unsigned short*)ws; ws += (long)D * D * 2;
    unsigned short* Sb  = (unsigned short*)ws; ws += Bq * SS * 2;

    unsigned short* Xb = Qb;                   // PV overwrites Qb with X bf16 (same-thread RMW)
    unsigned short* H  = Kb;                   // Kb dead after QK^T
    unsigned short* Yb = (unsigned short*)Sb;  // scores dead after PV

    // scratch in W1b/W2b region (weights converted after LN1 apply)
    char* sc = (char*)W1b;
    float* stats   = (float*)sc;               // 1 MB  (QK^T partial sums)
    float* stats_s = (float*)(sc + 0x140000);  // 512 KB (LN1 sum partials)
    float* stats_q = (float*)(sc + 0x1C0000);  // 512 KB (LN1 sumsq partials)

    const int DYN_LDS = 140288;  // 128 KiB bufs + 8 KB epilogue scratch + 1 KB invL
    (void)hipFuncSetAttribute(reinterpret_cast<const void*>(&gemm256<0>),
                              hipFuncAttributeMaxDynamicSharedMemorySize, DYN_LDS);
    (void)hipFuncSetAttribute(reinterpret_cast<const void*>(&gemm256<1>),
                              hipFuncAttributeMaxDynamicSharedMemorySize, DYN_LDS);
    (void)hipFuncSetAttribute(reinterpret_cast<const void*>(&gemm256<2>),
                              hipFuncAttributeMaxDynamicSharedMemorySize, DYN_LDS);
    (void)hipFuncSetAttribute(reinterpret_cast<const void*>(&gemm256<3>),
                              hipFuncAttributeMaxDynamicSharedMemorySize, DYN_LDS);

    const float scale = 1.0f / (sqrtf((float)D) + 1e-8f);
    const float rescale = sqrtf((float)D) + 1e-8f;

    cvt2_kernel<<<2048, 256, 0, stream>>>(Q, Qb, Bq * SD, scale, Kin, Kb, Bq * SD);
    transpose_kernel<<<dim3(S / 32, D / 32, Bq), 256, 0, stream>>>(V, Vt, S, D);

    // QK^T + exp + partial sums: 1024 tiles, TPB=4 -> 256 blocks (1/CU)
    gemm256<0><<<256, 512, DYN_LDS, stream>>>(
        Qb, Kb, Sb, stats, nullptr, nullptr, nullptr, 8, 8, S, D, SD, SD, SS, 1.0f, 4);

    // PV: invL from stats in prologue; X bf16 over Qb + LN1 partials: 512 tiles, TPB=2
    gemm256<1><<<256, 512, DYN_LDS, stream>>>(
        Sb, Vt, Xb, (const float*)Qb, stats, stats_s, stats_q, 4, 8, D, S, SS, SD, SD,
        rescale, 2);
    ln_apply_kernel<<<16384, 256, 0, stream>>>(Xb, stats_s, stats_q, gamma, beta);

    cvt2_kernel<<<512, 256, 0, stream>>>(W1, W1b, (long)D * D, 1.0f, W2, W2b, (long)D * D);

    // FFN: 512 tiles each, TPB=2 -> 256 blocks
    gemm256<2><<<256, 512, DYN_LDS, stream>>>(
        Xb, W1b, H, b1, nullptr, nullptr, nullptr, 4, 128, D, D, 0, 0, 0, 1.0f, 2);
    gemm256<3><<<256, 512, DYN_LDS, stream>>>(
        H, W2b, Yb, b2, (const float*)Xb, nullptr, nullptr, 4, 128, D, D, 0, 0, 0, 1.0f, 2);
    ln_final_kernel<<<rows, 256, 0, stream>>>(Yb, gamma, beta, out);
}

// Round 9
// 630.967 us; speedup vs baseline: 1.0122x; 1.0122x over previous
//
#include <hip/hip_runtime.h>
#include <cmath>
#include <cstdint>

#define LN_EPS 1e-5f

typedef __bf16 bf16x8 __attribute__((ext_vector_type(8)));
typedef float f32x4 __attribute__((ext_vector_type(4)));
typedef unsigned short u16x8 __attribute__((ext_vector_type(8)));
typedef unsigned short u16x4 __attribute__((ext_vector_type(4)));

__device__ inline float b2f(unsigned short u) {
    union { unsigned int ui; float f; } x; x.ui = ((unsigned int)u) << 16; return x.f;
}
__device__ inline unsigned short f2b(float f) {
    union { float f; unsigned int ui; } x; x.f = f;
    unsigned int u = x.ui;
    return (unsigned short)((u + 0x7FFFu + ((u >> 16) & 1u)) >> 16);  // RNE
}

// ---------------- fused fp32 -> bf16 convert of two arrays ----------------
__global__ void cvt2_kernel(const float* __restrict__ ia, unsigned short* __restrict__ oa,
                            long na, float sa,
                            const float* __restrict__ ib, unsigned short* __restrict__ ob,
                            long nb) {
    long i = ((long)blockIdx.x * blockDim.x + threadIdx.x) * 8;
    long stride = (long)gridDim.x * blockDim.x * 8;
    long n = na + nb;
    for (; i < n; i += stride) {
        const float* in; unsigned short* out; long j; float s;
        if (i < na) { in = ia; out = oa; j = i; s = sa; }
        else        { in = ib; out = ob; j = i - na; s = 1.0f; }
        float4 a = *reinterpret_cast<const float4*>(in + j);
        float4 b = *reinterpret_cast<const float4*>(in + j + 4);
        u16x8 o;
        o[0] = f2b(a.x * s); o[1] = f2b(a.y * s); o[2] = f2b(a.z * s); o[3] = f2b(a.w * s);
        o[4] = f2b(b.x * s); o[5] = f2b(b.y * s); o[6] = f2b(b.z * s); o[7] = f2b(b.w * s);
        *reinterpret_cast<u16x8*>(out + j) = o;
    }
}

// ---------------- V (B,S,D) fp32 -> Vt (B,D,S) bf16 ----------------
__global__ void transpose_kernel(const float* __restrict__ V, unsigned short* __restrict__ Vt,
                                 int S, int D) {
    __shared__ float t[32][33];
    int b = blockIdx.z;
    int s0 = blockIdx.x * 32, d0 = blockIdx.y * 32;
    int tx = threadIdx.x & 31, ty = threadIdx.x >> 5;
    const float* Vb = V + (long)b * S * D;
    unsigned short* Vtb = Vt + (long)b * S * D;
#pragma unroll
    for (int r = 0; r < 4; ++r)
        t[ty + r * 8][tx] = Vb[(long)(s0 + ty + r * 8) * D + d0 + tx];
    __syncthreads();
#pragma unroll
    for (int r = 0; r < 4; ++r)
        Vtb[(long)(d0 + ty + r * 8) * S + s0 + tx] = f2b(t[tx][ty + r * 8]);
}

// ======= 256x256 8-wave NT GEMM: R7 grid/swizzle, 3-phase single-barrier body =======
// MODE 0: QK^T: p=exp(s) bf16 unnormalized; partial row sums -> aux1
// MODE 1: X = acc*invL[row](aux2) + b2f(Qb[idx])*scale(aux1); bf16; LN1 partials -> aux3/4
// MODE 2: H = bf16(relu(acc + aux1[n]))                   (aux1 = b1)
// MODE 3: Y = bf16(acc + aux1[n] + b2f(aux2_bf16[idx]))   (aux1 = b2, aux2 = Xb)
#define GBK 64

__device__ inline void gload16(const unsigned short* g, unsigned short* l) {
    __builtin_amdgcn_global_load_lds((const __attribute__((address_space(1))) void*)g,
                                     (__attribute__((address_space(3))) void*)l, 16, 0, 0);
}

__device__ inline void stage_half(const unsigned short* gRowBase, int ldk, int k0,
                                  unsigned short* ldsHalf, int tid) {
#pragma unroll
    for (int l = 0; l < 2; ++l) {
        int g = l * 512 + tid;
        int row = g >> 3;
        int lg = (g & 7) ^ (row & 7);
        gload16(gRowBase + (long)row * ldk + k0 + lg * 8, ldsHalf + g * 8);
    }
}

__device__ inline bf16x8 frag_ld(const unsigned short* ldsHalf, int rowInHalf, int kgran) {
    int sw = kgran ^ (rowInHalf & 7);
    return *reinterpret_cast<const bf16x8*>(ldsHalf + rowInHalf * 64 + sw * 8);
}

#define GMFMA(am, bn, mi, ni) \
    acc[mi][ni] = __builtin_amdgcn_mfma_f32_16x16x32_bf16(am, bn, acc[mi][ni], 0, 0, 0)

template <int MODE>
__global__ __launch_bounds__(512, 1) void gemm256(
    const unsigned short* __restrict__ A, const unsigned short* __restrict__ B,
    void* __restrict__ Cout, const float* __restrict__ aux1, const float* __restrict__ aux2,
    float* __restrict__ aux3, float* __restrict__ aux4,
    int tX, int tY, int N, int K, long bsA, long bsB, long bsC, float scale) {
    extern __shared__ __align__(16) unsigned short lds[];
    // chunked XCD swizzle (gridDim.x % 8 == 0) — R7-verified L2 mapping
    const int cpx = gridDim.x >> 3;
    const int swz = (blockIdx.x & 7) * cpx + (blockIdx.x >> 3);
    const int bx = swz % tX;
    const int t2 = swz / tX;
    const int by = t2 % tY, bz = t2 / tY;

    const unsigned short* Ab = A + (long)bz * bsA + (long)by * 256 * K;
    const unsigned short* Bb = B + (long)bz * bsB + (long)bx * 256 * K;
    const int tid = threadIdx.x;
    const int wid = tid >> 6, lane = tid & 63;
    const int wr = wid >> 2, wc = wid & 3;
    const int lr = lane & 15, kq = lane >> 4;
    const int NT = K >> 6;
    const int ccol = lane & 15, crow0 = kq * 4;
    const long m0 = (long)by * 256 + wr * 128;
    const long n0 = (long)bx * 256 + wc * 64;
    const int bRow0 = (wc & 1) * 64;

#define STAGE_A(tile, half) stage_half(Ab + (long)(half) * 128 * K, K, (tile) * GBK, \
        lds + (((tile) & 1) * 32768 + (half) * 8192), tid)
#define STAGE_B(tile, half) stage_half(Bb + (long)(half) * 128 * K, K, (tile) * GBK, \
        lds + (((tile) & 1) * 32768 + 16384 + (half) * 8192), tid)

    f32x4 acc[8][4];
#pragma unroll
    for (int i = 0; i < 8; ++i)
#pragma unroll
        for (int j = 0; j < 4; ++j) acc[i][j] = (f32x4){0.f, 0.f, 0.f, 0.f};
    bf16x8 a[4][2], b[4][2];

    // prologue: tile0 all halves + tile1 h0 halves (2 gloads per stage -> vmcnt(4)
    // forces tile0's 4 halves complete, leaves tile1-h0 pair in flight)
    STAGE_A(0, 0); STAGE_A(0, 1); STAGE_B(0, 0); STAGE_B(0, 1);
    STAGE_B(1, 0); STAGE_A(1, 0);
    asm volatile("s_waitcnt vmcnt(4)" ::: "memory");
    __builtin_amdgcn_s_barrier();

    for (int t = 0; t < NT; ++t) {
        const unsigned short* aB = lds + ((t & 1) * 32768 + wr * 8192);
        const unsigned short* bB = lds + ((t & 1) * 32768 + 16384 + (wc >> 1) * 8192);
        // ---- P1: read alo + b01; stage A-h1(t+1); one barrier; MFMA Q00 ----
#pragma unroll
        for (int m = 0; m < 4; ++m)
#pragma unroll
            for (int ks = 0; ks < 2; ++ks)
                a[m][ks] = frag_ld(aB, m * 16 + lr, ks * 4 + kq);
#pragma unroll
        for (int n = 0; n < 2; ++n)
#pragma unroll
            for (int ks = 0; ks < 2; ++ks)
                b[n][ks] = frag_ld(bB, bRow0 + n * 16 + lr, ks * 4 + kq);
        if (t + 1 < NT) STAGE_A(t + 1, 1);
        __builtin_amdgcn_s_barrier();
        asm volatile("s_waitcnt lgkmcnt(0)" ::: "memory");
        __builtin_amdgcn_sched_barrier(0);
        __builtin_amdgcn_s_setprio(1);
#pragma unroll
        for (int m = 0; m < 4; ++m)
#pragma unroll
            for (int n = 0; n < 2; ++n)
#pragma unroll
                for (int ks = 0; ks < 2; ++ks) GMFMA(a[m][ks], b[n][ks], m, n);
        __builtin_amdgcn_s_setprio(0);
        // ---- P2: read b23; stage B-h1(t+1); one barrier; MFMA Q01 ----
#pragma unroll
        for (int n = 0; n < 2; ++n)
#pragma unroll
            for (int ks = 0; ks < 2; ++ks)
                b[2 + n][ks] = frag_ld(bB, bRow0 + (2 + n) * 16 + lr, ks * 4 + kq);
        if (t + 1 < NT) STAGE_B(t + 1, 1);
        __builtin_amdgcn_s_barrier();
        asm volatile("s_waitcnt lgkmcnt(0)" ::: "memory");
        __builtin_amdgcn_sched_barrier(0);
        __builtin_amdgcn_s_setprio(1);
#pragma unroll
        for (int m = 0; m < 4; ++m)
#pragma unroll
            for (int n = 0; n < 2; ++n)
#pragma unroll
                for (int ks = 0; ks < 2; ++ks) GMFMA(a[m][ks], b[2 + n][ks], m, 2 + n);
        __builtin_amdgcn_s_setprio(0);
        // ---- P3 (merged): read ahi; stage h0(t+2) x2; counted vmcnt; MFMA Q10+Q11 ----
#pragma unroll
        for (int m = 0; m < 4; ++m)
#pragma unroll
            for (int ks = 0; ks < 2; ++ks)
                a[m][ks] = frag_ld(aB, 64 + m * 16 + lr, ks * 4 + kq);
        if (t + 2 < NT) { STAGE_B(t + 2, 0); STAGE_A(t + 2, 0); }
        if (t < NT - 2) asm volatile("s_waitcnt vmcnt(4)" ::: "memory");
        else            asm volatile("s_waitcnt vmcnt(0)" ::: "memory");
        __builtin_amdgcn_s_barrier();
        asm volatile("s_waitcnt lgkmcnt(0)" ::: "memory");
        __builtin_amdgcn_sched_barrier(0);
        __builtin_amdgcn_s_setprio(1);
#pragma unroll
        for (int m = 0; m < 4; ++m)
#pragma unroll
            for (int n = 0; n < 2; ++n)
#pragma unroll
                for (int ks = 0; ks < 2; ++ks) GMFMA(a[m][ks], b[n][ks], 4 + m, n);
#pragma unroll
        for (int m = 0; m < 4; ++m)
#pragma unroll
            for (int n = 0; n < 2; ++n)
#pragma unroll
                for (int ks = 0; ks < 2; ++ks) GMFMA(a[m][ks], b[2 + n][ks], 4 + m, 2 + n);
        __builtin_amdgcn_s_setprio(0);
    }
    // NT is even -> final reads hit buf1; epilogue scratch lives in buf0 (disjoint)

    if (MODE == 0) {
        float* sl = (float*)lds;
        unsigned short* Pout = (unsigned short*)Cout;
#pragma unroll
        for (int m = 0; m < 8; ++m) {
            float ls[4] = {0.f, 0.f, 0.f, 0.f};
#pragma unroll
            for (int n = 0; n < 4; ++n) {
                long gn = n0 + n * 16 + ccol;
#pragma unroll
                for (int r = 0; r < 4; ++r) {
                    float p = __expf(acc[m][n][r]);
                    ls[r] += p;
                    Pout[bz * bsC + (m0 + m * 16 + crow0 + r) * N + gn] = f2b(p);
                }
            }
#pragma unroll
            for (int r = 0; r < 4; ++r)
#pragma unroll
                for (int off = 8; off >= 1; off >>= 1) ls[r] += __shfl_xor(ls[r], off, 64);
            if ((lane & 15) == 0)
#pragma unroll
                for (int r = 0; r < 4; ++r)
                    sl[wc * 256 + wr * 128 + m * 16 + crow0 + r] = ls[r];
        }
        __syncthreads();
        if (wc == 0) {
#pragma unroll
            for (int rep = 0; rep < 2; ++rep) {
                int rowB = wr * 128 + rep * 64 + lane;
                float s4 = sl[0 * 256 + rowB] + sl[1 * 256 + rowB] +
                           sl[2 * 256 + rowB] + sl[3 * 256 + rowB];
                ((float*)aux1)[((long)bz * 8 + bx) * 2048 + by * 256 + rowB] = s4;
            }
        }
        return;
    }

    if (MODE == 1) {
        const float* il = aux2 + (long)bz * 2048 + m0;
        float* sls = (float*)lds;
        float* slq = sls + 1024;
        unsigned short* Xout = (unsigned short*)Cout;
#pragma unroll
        for (int m = 0; m < 8; ++m) {
            float ls[4] = {0.f, 0.f, 0.f, 0.f}, lq[4] = {0.f, 0.f, 0.f, 0.f};
#pragma unroll
            for (int r = 0; r < 4; ++r) {
                float cf = il[m * 16 + crow0 + r];
                long gm = m0 + m * 16 + crow0 + r;
#pragma unroll
                for (int n = 0; n < 4; ++n) {
                    long gn = n0 + n * 16 + ccol;
                    long idx = bz * bsC + gm * N + gn;
                    float v = acc[m][n][r] * cf +
                              b2f(((const unsigned short*)aux1)[idx]) * scale;
                    Xout[idx] = f2b(v);
                    ls[r] += v; lq[r] += v * v;
                }
            }
#pragma unroll
            for (int r = 0; r < 4; ++r)
#pragma unroll
                for (int off = 8; off >= 1; off >>= 1) {
                    ls[r] += __shfl_xor(ls[r], off, 64);
                    lq[r] += __shfl_xor(lq[r], off, 64);
                }
            if ((lane & 15) == 0)
#pragma unroll
                for (int r = 0; r < 4; ++r) {
                    sls[wc * 256 + wr * 128 + m * 16 + crow0 + r] = ls[r];
                    slq[wc * 256 + wr * 128 + m * 16 + crow0 + r] = lq[r];
                }
        }
        __syncthreads();
        if (wc == 0) {
#pragma unroll
            for (int rep = 0; rep < 2; ++rep) {
                int rowB = wr * 128 + rep * 64 + lane;
                float s4 = sls[rowB] + sls[256 + rowB] + sls[512 + rowB] + sls[768 + rowB];
                float q4 = slq[rowB] + slq[256 + rowB] + slq[512 + rowB] + slq[768 + rowB];
                long sidx = ((long)bz * 4 + bx) * 2048 + by * 256 + rowB;
                aux3[sidx] = s4;
                aux4[sidx] = q4;
            }
        }
        return;
    }

#pragma unroll
    for (int m = 0; m < 8; ++m) {
#pragma unroll
        for (int n = 0; n < 4; ++n) {
            long gn = n0 + n * 16 + ccol;
#pragma unroll
            for (int r = 0; r < 4; ++r) {
                long gm = m0 + m * 16 + crow0 + r;
                float v = acc[m][n][r];
                if (MODE == 2) {
                    ((unsigned short*)Cout)[gm * N + gn] = f2b(fmaxf(v + aux1[gn], 0.f));
                } else {  // MODE 3
                    long idx = gm * N + gn;
                    ((unsigned short*)Cout)[idx] =
                        f2b(v + aux1[gn] + b2f(((const unsigned short*)aux2)[idx]));
                }
            }
        }
    }
#undef STAGE_A
#undef STAGE_B
}

// ---------------- combine per-tile partial sums -> 1/L per row ----------------
__global__ void suminv_kernel(const float* __restrict__ stats, float* __restrict__ invL) {
    int i = blockIdx.x * 256 + threadIdx.x;  // 32768 = 16 * 2048
    int bz = i >> 11, row = i & 2047;
    long base = (long)bz * 8 * 2048 + row;
    float L = 0.f;
#pragma unroll
    for (int t = 0; t < 8; ++t) L += stats[base + t * 2048];
    invL[i] = 1.f / L;
}

// ---------------- LN1 apply with inline stats combine (bf16 in-place) ----------------
__global__ void ln_apply_kernel(unsigned short* __restrict__ X, const float* __restrict__ ss,
                                const float* __restrict__ sq, const float* __restrict__ gamma,
                                const float* __restrict__ beta) {
    __shared__ float mr[4];
    int tid = threadIdx.x;
    long rowbase = (long)blockIdx.x * 2;  // 2 rows / block
    if (tid < 2) {
        long row = rowbase + tid;
        int bz = (int)(row >> 11), lrow = (int)(row & 2047);
        long base = (long)bz * 4 * 2048 + lrow;
        float s = 0.f, q = 0.f;
#pragma unroll
        for (int t = 0; t < 4; ++t) { s += ss[base + t * 2048]; q += sq[base + t * 2048]; }
        float m = s * (1.f / 1024.f);
        float var = q * (1.f / 1024.f) - m * m;
        mr[tid * 2] = m;
        mr[tid * 2 + 1] = rsqrtf(var + LN_EPS);
    }
    __syncthreads();
    int sub = tid >> 7;
    float m = mr[sub * 2], r = mr[sub * 2 + 1];
    long i = rowbase * 1024 + (long)tid * 8;
    int col = (tid * 8) & 1023;
    u16x8 raw = *reinterpret_cast<const u16x8*>(X + i);
    float4 g0 = *reinterpret_cast<const float4*>(gamma + col);
    float4 g1 = *reinterpret_cast<const float4*>(gamma + col + 4);
    float4 b0 = *reinterpret_cast<const float4*>(beta + col);
    float4 b1 = *reinterpret_cast<const float4*>(beta + col + 4);
    u16x8 o;
    o[0] = f2b((b2f(raw[0]) - m) * r * g0.x + b0.x);
    o[1] = f2b((b2f(raw[1]) - m) * r * g0.y + b0.y);
    o[2] = f2b((b2f(raw[2]) - m) * r * g0.z + b0.z);
    o[3] = f2b((b2f(raw[3]) - m) * r * g0.w + b0.w);
    o[4] = f2b((b2f(raw[4]) - m) * r * g1.x + b1.x);
    o[5] = f2b((b2f(raw[5]) - m) * r * g1.y + b1.y);
    o[6] = f2b((b2f(raw[6]) - m) * r * g1.z + b1.z);
    o[7] = f2b((b2f(raw[7]) - m) * r * g1.w + b1.w);
    *reinterpret_cast<u16x8*>(X + i) = o;
}

// ---------------- final LayerNorm: bf16 rows in, fp32 out ----------------
__device__ inline float wave_sum(float v) {
#pragma unroll
    for (int off = 32; off > 0; off >>= 1) v += __shfl_xor(v, off, 64);
    return v;
}

__global__ void ln_final_kernel(const unsigned short* __restrict__ Yb,
                                const float* __restrict__ gamma, const float* __restrict__ beta,
                                float* __restrict__ out) {
    __shared__ float red[8];
    long row = blockIdx.x;
    const unsigned short* y = Yb + row * 1024;
    int tid = threadIdx.x;
    int wv = tid >> 6, ln = tid & 63;
    u16x4 raw = *reinterpret_cast<const u16x4*>(y + tid * 4);
    float v0 = b2f(raw[0]), v1 = b2f(raw[1]), v2 = b2f(raw[2]), v3 = b2f(raw[3]);
    float s = v0 + v1 + v2 + v3;
    float q = v0 * v0 + v1 * v1 + v2 * v2 + v3 * v3;
    s = wave_sum(s);
    q = wave_sum(q);
    if (ln == 0) { red[wv] = s; red[4 + wv] = q; }
    __syncthreads();
    s = red[0] + red[1] + red[2] + red[3];
    q = red[4] + red[5] + red[6] + red[7];
    float mu = s * (1.f / 1024.f);
    float var = q * (1.f / 1024.f) - mu * mu;
    float rsg = rsqrtf(var + LN_EPS);
    float4 g = *reinterpret_cast<const float4*>(gamma + tid * 4);
    float4 b = *reinterpret_cast<const float4*>(beta + tid * 4);
    float4 o;
    o.x = (v0 - mu) * rsg * g.x + b.x;
    o.y = (v1 - mu) * rsg * g.y + b.y;
    o.z = (v2 - mu) * rsg * g.z + b.z;
    o.w = (v3 - mu) * rsg * g.w + b.w;
    *reinterpret_cast<float4*>(out + row * 1024 + tid * 4) = o;
}

extern "C" void kernel_launch(void* const* d_in, const int* in_sizes, int n_in,
                              void* d_out, int out_size, void* d_ws, size_t ws_size,
                              hipStream_t stream) {
    const float* Q     = (const float*)d_in[0];
    const float* Kin   = (const float*)d_in[1];
    const float* V     = (const float*)d_in[2];
    const float* W1    = (const float*)d_in[3];
    const float* b1    = (const float*)d_in[4];
    const float* W2    = (const float*)d_in[5];
    const float* b2    = (const float*)d_in[6];
    const float* gamma = (const float*)d_in[7];
    const float* beta  = (const float*)d_in[8];
    float* out = (float*)d_out;

    const int Bq = 16, S = 2048, D = 1024;
    const long SD = (long)S * D;
    const long SS = (long)S * S;
    const long rows = (long)Bq * S;  // 32768

    const size_t NEED = 3 * (size_t)(Bq * SD * 2) + 2 * (size_t)D * D * 2 + (size_t)(Bq * SS * 2);
    if (ws_size < NEED) return;

    char* ws = (char*)d_ws;
    unsigned short* Qb  = (unsigned short*)ws; ws += Bq * SD * 2;
    unsigned short* Kb  = (unsigned short*)ws; ws += Bq * SD * 2;
    unsigned short* Vt  = (unsigned short*)ws; ws += Bq * SD * 2;
    unsigned short* W1b = (unsigned short*)ws; ws += (long)D * D * 2;
    unsigned short* W2b = (unsigned short*)ws; ws += (long)D * D * 2;
    unsigned short* Sb  = (unsigned short*)ws; ws += Bq * SS * 2;

    unsigned short* Xb = Qb;                   // PV overwrites Qb with X bf16 (same-thread RMW)
    unsigned short* H  = Kb;                   // Kb dead after QK^T
    unsigned short* Yb = (unsigned short*)Sb;  // scores dead after PV

    // scratch in W1b/W2b region (weights converted after LN1 apply)
    char* sc = (char*)W1b;
    float* stats   = (float*)sc;               // 1 MB  (QK^T partial sums)
    float* invL    = (float*)(sc + 0x100000);  // 128 KB
    float* stats_s = (float*)(sc + 0x140000);  // 512 KB (LN1 sum partials)
    float* stats_q = (float*)(sc + 0x1C0000);  // 512 KB (LN1 sumsq partials)

    const int DYN_LDS = 131072;
    (void)hipFuncSetAttribute(reinterpret_cast<const void*>(&gemm256<0>),
                              hipFuncAttributeMaxDynamicSharedMemorySize, DYN_LDS);
    (void)hipFuncSetAttribute(reinterpret_cast<const void*>(&gemm256<1>),
                              hipFuncAttributeMaxDynamicSharedMemorySize, DYN_LDS);
    (void)hipFuncSetAttribute(reinterpret_cast<const void*>(&gemm256<2>),
                              hipFuncAttributeMaxDynamicSharedMemorySize, DYN_LDS);
    (void)hipFuncSetAttribute(reinterpret_cast<const void*>(&gemm256<3>),
                              hipFuncAttributeMaxDynamicSharedMemorySize, DYN_LDS);

    const float scale = 1.0f / (sqrtf((float)D) + 1e-8f);
    const float rescale = sqrtf((float)D) + 1e-8f;

    cvt2_kernel<<<2048, 256, 0, stream>>>(Q, Qb, Bq * SD, scale, Kin, Kb, Bq * SD);
    transpose_kernel<<<dim3(S / 32, D / 32, Bq), 256, 0, stream>>>(V, Vt, S, D);

    // QK^T + exp + partial sums  (tX=8, tY=8, 16 bz -> 1024 blocks)
    gemm256<0><<<1024, 512, DYN_LDS, stream>>>(
        Qb, Kb, Sb, stats, nullptr, nullptr, nullptr, 8, 8, S, D, SD, SD, SS, 1.0f);
    suminv_kernel<<<128, 256, 0, stream>>>(stats, invL);

    // PV * invL + Q residual -> X bf16 (over Qb) + LN1 partials  (tX=4, tY=8 -> 512)
    gemm256<1><<<512, 512, DYN_LDS, stream>>>(
        Sb, Vt, Xb, (const float*)Qb, invL, stats_s, stats_q, 4, 8, D, S, SS, SD, SD, rescale);
    ln_apply_kernel<<<16384, 256, 0, stream>>>(Xb, stats_s, stats_q, gamma, beta);

    cvt2_kernel<<<512, 256, 0, stream>>>(W1, W1b, (long)D * D, 1.0f, W2, W2b, (long)D * D);

    // FFN  (tX=4, tY=128 -> 512 blocks each)
    gemm256<2><<<512, 512, DYN_LDS, stream>>>(
        Xb, W1b, H, b1, nullptr, nullptr, nullptr, 4, 128, D, D, 0, 0, 0, 1.0f);
    gemm256<3><<<512, 512, DYN_LDS, stream>>>(
        H, W2b, Yb, b2, (const float*)Xb, nullptr, nullptr, 4, 128, D, D, 0, 0, 0, 1.0f);
    ln_final_kernel<<<rows, 256, 0, stream>>>(Yb, gamma, beta, out);
}

// Round 10
// 617.017 us; speedup vs baseline: 1.0351x; 1.0226x over previous
//
#include <hip/hip_runtime.h>
#include <cmath>
#include <cstdint>

#define LN_EPS 1e-5f

typedef __bf16 bf16x8 __attribute__((ext_vector_type(8)));
typedef float f32x4 __attribute__((ext_vector_type(4)));
typedef unsigned short u16x8 __attribute__((ext_vector_type(8)));
typedef unsigned short u16x4 __attribute__((ext_vector_type(4)));

__device__ inline float b2f(unsigned short u) {
    union { unsigned int ui; float f; } x; x.ui = ((unsigned int)u) << 16; return x.f;
}
__device__ inline unsigned short f2b(float f) {
    union { float f; unsigned int ui; } x; x.f = f;
    unsigned int u = x.ui;
    return (unsigned short)((u + 0x7FFFu + ((u >> 16) & 1u)) >> 16);  // RNE
}

// ---------------- fused fp32 -> bf16 convert of two arrays ----------------
__global__ void cvt2_kernel(const float* __restrict__ ia, unsigned short* __restrict__ oa,
                            long na, float sa,
                            const float* __restrict__ ib, unsigned short* __restrict__ ob,
                            long nb) {
    long i = ((long)blockIdx.x * blockDim.x + threadIdx.x) * 8;
    long stride = (long)gridDim.x * blockDim.x * 8;
    long n = na + nb;
    for (; i < n; i += stride) {
        const float* in; unsigned short* out; long j; float s;
        if (i < na) { in = ia; out = oa; j = i; s = sa; }
        else        { in = ib; out = ob; j = i - na; s = 1.0f; }
        float4 a = *reinterpret_cast<const float4*>(in + j);
        float4 b = *reinterpret_cast<const float4*>(in + j + 4);
        u16x8 o;
        o[0] = f2b(a.x * s); o[1] = f2b(a.y * s); o[2] = f2b(a.z * s); o[3] = f2b(a.w * s);
        o[4] = f2b(b.x * s); o[5] = f2b(b.y * s); o[6] = f2b(b.z * s); o[7] = f2b(b.w * s);
        *reinterpret_cast<u16x8*>(out + j) = o;
    }
}

// ---------------- V (B,S,D) fp32 -> Vt (B,D,S) bf16 ----------------
__global__ void transpose_kernel(const float* __restrict__ V, unsigned short* __restrict__ Vt,
                                 int S, int D) {
    __shared__ float t[32][33];
    int b = blockIdx.z;
    int s0 = blockIdx.x * 32, d0 = blockIdx.y * 32;
    int tx = threadIdx.x & 31, ty = threadIdx.x >> 5;
    const float* Vb = V + (long)b * S * D;
    unsigned short* Vtb = Vt + (long)b * S * D;
#pragma unroll
    for (int r = 0; r < 4; ++r)
        t[ty + r * 8][tx] = Vb[(long)(s0 + ty + r * 8) * D + d0 + tx];
    __syncthreads();
#pragma unroll
    for (int r = 0; r < 4; ++r)
        Vtb[(long)(d0 + ty + r * 8) * S + s0 + tx] = f2b(t[tx][ty + r * 8]);
}

// ======= 256x256 8-wave NT GEMM: R7 grid/swizzle + register read-ahead body =======
// MODE 0: QK^T: p=exp(s) bf16 unnormalized; partial row sums -> aux1
// MODE 1: X = acc*invL[row](aux2) + b2f(Qb[idx])*scale(aux1); bf16; LN1 partials -> aux3/4
// MODE 2: H = bf16(relu(acc + aux1[n]))                   (aux1 = b1)
// MODE 3: Y = bf16(acc + aux1[n] + b2f(aux2_bf16[idx]))   (aux1 = b2, aux2 = Xb)
#define GBK 64

__device__ inline void gload16(const unsigned short* g, unsigned short* l) {
    __builtin_amdgcn_global_load_lds((const __attribute__((address_space(1))) void*)g,
                                     (__attribute__((address_space(3))) void*)l, 16, 0, 0);
}

__device__ inline void stage_half(const unsigned short* gRowBase, int ldk, int k0,
                                  unsigned short* ldsHalf, int tid) {
#pragma unroll
    for (int l = 0; l < 2; ++l) {
        int g = l * 512 + tid;
        int row = g >> 3;
        int lg = (g & 7) ^ (row & 7);
        gload16(gRowBase + (long)row * ldk + k0 + lg * 8, ldsHalf + g * 8);
    }
}

__device__ inline bf16x8 frag_ld(const unsigned short* ldsHalf, int rowInHalf, int kgran) {
    int sw = kgran ^ (rowInHalf & 7);
    return *reinterpret_cast<const bf16x8*>(ldsHalf + rowInHalf * 64 + sw * 8);
}

#define GMFMA(am, bn, mi, ni) \
    acc[mi][ni] = __builtin_amdgcn_mfma_f32_16x16x32_bf16(am, bn, acc[mi][ni], 0, 0, 0)

template <int MODE>
__global__ __launch_bounds__(512, 1) void gemm256(
    const unsigned short* __restrict__ A, const unsigned short* __restrict__ B,
    void* __restrict__ Cout, const float* __restrict__ aux1, const float* __restrict__ aux2,
    float* __restrict__ aux3, float* __restrict__ aux4,
    int tX, int tY, int N, int K, long bsA, long bsB, long bsC, float scale) {
    extern __shared__ __align__(16) unsigned short lds[];
    // chunked XCD swizzle (gridDim.x % 8 == 0) — R7-verified L2 mapping
    const int cpx = gridDim.x >> 3;
    const int swz = (blockIdx.x & 7) * cpx + (blockIdx.x >> 3);
    const int bx = swz % tX;
    const int t2 = swz / tX;
    const int by = t2 % tY, bz = t2 / tY;

    const unsigned short* Ab = A + (long)bz * bsA + (long)by * 256 * K;
    const unsigned short* Bb = B + (long)bz * bsB + (long)bx * 256 * K;
    const int tid = threadIdx.x;
    const int wid = tid >> 6, lane = tid & 63;
    const int wr = wid >> 2, wc = wid & 3;
    const int lr = lane & 15, kq = lane >> 4;
    const int NT = K >> 6;
    const int ccol = lane & 15, crow0 = kq * 4;
    const long m0 = (long)by * 256 + wr * 128;
    const long n0 = (long)bx * 256 + wc * 64;
    const int bRow0 = (wc & 1) * 64;

#define STAGE_A(tile, half) stage_half(Ab + (long)(half) * 128 * K, K, (tile) * GBK, \
        lds + (((tile) & 1) * 32768 + (half) * 8192), tid)
#define STAGE_B(tile, half) stage_half(Bb + (long)(half) * 128 * K, K, (tile) * GBK, \
        lds + (((tile) & 1) * 32768 + 16384 + (half) * 8192), tid)

    f32x4 acc[8][4];
#pragma unroll
    for (int i = 0; i < 8; ++i)
#pragma unroll
        for (int j = 0; j < 4; ++j) acc[i][j] = (f32x4){0.f, 0.f, 0.f, 0.f};
    bf16x8 alo[4][2], ahi[4][2], b01[2][2], b23[2][2];

    // prologue: tile0 all 4 halves + tile1 h0 pair; vmcnt(4) leaves tile1-h0 in flight
    STAGE_A(0, 0); STAGE_A(0, 1); STAGE_B(0, 0); STAGE_B(0, 1);
    STAGE_B(1, 0); STAGE_A(1, 0);
    asm volatile("s_waitcnt vmcnt(4)" ::: "memory");
    __builtin_amdgcn_s_barrier();

    {   // preload t=0 fragments for Q00
        const unsigned short* aB = lds + wr * 8192;
        const unsigned short* bB = lds + 16384 + (wc >> 1) * 8192;
#pragma unroll
        for (int m = 0; m < 4; ++m)
#pragma unroll
            for (int ks = 0; ks < 2; ++ks) alo[m][ks] = frag_ld(aB, m * 16 + lr, ks * 4 + kq);
#pragma unroll
        for (int n = 0; n < 2; ++n)
#pragma unroll
            for (int ks = 0; ks < 2; ++ks) b01[n][ks] = frag_ld(bB, bRow0 + n * 16 + lr, ks * 4 + kq);
    }

    for (int t = 0; t < NT; ++t) {
        const unsigned short* aB = lds + ((t & 1) * 32768 + wr * 8192);
        const unsigned short* bB = lds + ((t & 1) * 32768 + 16384 + (wc >> 1) * 8192);
        // ---- R1: read b23 (for Q01) ; stage A-h1(t+1) ; MFMA Q00(alo,b01) ----
#pragma unroll
        for (int n = 0; n < 2; ++n)
#pragma unroll
            for (int ks = 0; ks < 2; ++ks)
                b23[n][ks] = frag_ld(bB, bRow0 + (2 + n) * 16 + lr, ks * 4 + kq);
        if (t + 1 < NT) STAGE_A(t + 1, 1);
        __builtin_amdgcn_s_setprio(1);
#pragma unroll
        for (int m = 0; m < 4; ++m)
#pragma unroll
            for (int n = 0; n < 2; ++n)
#pragma unroll
                for (int ks = 0; ks < 2; ++ks) GMFMA(alo[m][ks], b01[n][ks], m, n);
        __builtin_amdgcn_s_setprio(0);
        __builtin_amdgcn_s_barrier();
        // ---- R2: read ahi (for Q10) ; stage B-h1(t+1) ; MFMA Q01(alo,b23) ----
#pragma unroll
        for (int m = 0; m < 4; ++m)
#pragma unroll
            for (int ks = 0; ks < 2; ++ks)
                ahi[m][ks] = frag_ld(aB, 64 + m * 16 + lr, ks * 4 + kq);
        if (t + 1 < NT) STAGE_B(t + 1, 1);
        __builtin_amdgcn_s_setprio(1);
#pragma unroll
        for (int m = 0; m < 4; ++m)
#pragma unroll
            for (int n = 0; n < 2; ++n)
#pragma unroll
                for (int ks = 0; ks < 2; ++ks) GMFMA(alo[m][ks], b23[n][ks], m, 2 + n);
        __builtin_amdgcn_s_setprio(0);
        __builtin_amdgcn_s_barrier();
        // ---- R3: stage B-h0(t+2) ; MFMA Q10(ahi,b01) ----
        if (t + 2 < NT) STAGE_B(t + 2, 0);
        __builtin_amdgcn_s_setprio(1);
#pragma unroll
        for (int m = 0; m < 4; ++m)
#pragma unroll
            for (int n = 0; n < 2; ++n)
#pragma unroll
                for (int ks = 0; ks < 2; ++ks) GMFMA(ahi[m][ks], b01[n][ks], 4 + m, n);
        __builtin_amdgcn_s_setprio(0);
        __builtin_amdgcn_s_barrier();
        // ---- R4: stage A-h0(t+2) ; counted vmcnt ; barrier ; preload t+1 alo/b01 ;
        //          MFMA Q11(ahi,b23) ----
        if (t + 2 < NT) STAGE_A(t + 2, 0);
        if (t < NT - 2) asm volatile("s_waitcnt vmcnt(4)" ::: "memory");
        else            asm volatile("s_waitcnt vmcnt(0)" ::: "memory");
        __builtin_amdgcn_s_barrier();
        if (t + 1 < NT) {
            const unsigned short* aBn = lds + (((t + 1) & 1) * 32768 + wr * 8192);
            const unsigned short* bBn = lds + (((t + 1) & 1) * 32768 + 16384 + (wc >> 1) * 8192);
#pragma unroll
            for (int m = 0; m < 4; ++m)
#pragma unroll
                for (int ks = 0; ks < 2; ++ks)
                    alo[m][ks] = frag_ld(aBn, m * 16 + lr, ks * 4 + kq);
#pragma unroll
            for (int n = 0; n < 2; ++n)
#pragma unroll
                for (int ks = 0; ks < 2; ++ks)
                    b01[n][ks] = frag_ld(bBn, bRow0 + n * 16 + lr, ks * 4 + kq);
        }
        __builtin_amdgcn_s_setprio(1);
#pragma unroll
        for (int m = 0; m < 4; ++m)
#pragma unroll
            for (int n = 0; n < 2; ++n)
#pragma unroll
                for (int ks = 0; ks < 2; ++ks) GMFMA(ahi[m][ks], b23[n][ks], 4 + m, 2 + n);
        __builtin_amdgcn_s_setprio(0);
    }
    __builtin_amdgcn_s_barrier();
    // NT even -> final tile's reads hit buf1; epilogue scratch uses buf0 (disjoint)

    if (MODE == 0) {
        float* sl = (float*)lds;
        unsigned short* Pout = (unsigned short*)Cout;
#pragma unroll
        for (int m = 0; m < 8; ++m) {
            float ls[4] = {0.f, 0.f, 0.f, 0.f};
#pragma unroll
            for (int n = 0; n < 4; ++n) {
                long gn = n0 + n * 16 + ccol;
#pragma unroll
                for (int r = 0; r < 4; ++r) {
                    float p = __expf(acc[m][n][r]);
                    ls[r] += p;
                    Pout[bz * bsC + (m0 + m * 16 + crow0 + r) * N + gn] = f2b(p);
                }
            }
#pragma unroll
            for (int r = 0; r < 4; ++r)
#pragma unroll
                for (int off = 8; off >= 1; off >>= 1) ls[r] += __shfl_xor(ls[r], off, 64);
            if ((lane & 15) == 0)
#pragma unroll
                for (int r = 0; r < 4; ++r)
                    sl[wc * 256 + wr * 128 + m * 16 + crow0 + r] = ls[r];
        }
        __syncthreads();
        if (wc == 0) {
#pragma unroll
            for (int rep = 0; rep < 2; ++rep) {
                int rowB = wr * 128 + rep * 64 + lane;
                float s4 = sl[0 * 256 + rowB] + sl[1 * 256 + rowB] +
                           sl[2 * 256 + rowB] + sl[3 * 256 + rowB];
                ((float*)aux1)[((long)bz * 8 + bx) * 2048 + by * 256 + rowB] = s4;
            }
        }
        return;
    }

    if (MODE == 1) {
        const float* il = aux2 + (long)bz * 2048 + m0;
        float* sls = (float*)lds;
        float* slq = sls + 1024;
        unsigned short* Xout = (unsigned short*)Cout;
#pragma unroll
        for (int m = 0; m < 8; ++m) {
            float ls[4] = {0.f, 0.f, 0.f, 0.f}, lq[4] = {0.f, 0.f, 0.f, 0.f};
#pragma unroll
            for (int r = 0; r < 4; ++r) {
                float cf = il[m * 16 + crow0 + r];
                long gm = m0 + m * 16 + crow0 + r;
#pragma unroll
                for (int n = 0; n < 4; ++n) {
                    long gn = n0 + n * 16 + ccol;
                    long idx = bz * bsC + gm * N + gn;
                    float v = acc[m][n][r] * cf +
                              b2f(((const unsigned short*)aux1)[idx]) * scale;
                    Xout[idx] = f2b(v);
                    ls[r] += v; lq[r] += v * v;
                }
            }
#pragma unroll
            for (int r = 0; r < 4; ++r)
#pragma unroll
                for (int off = 8; off >= 1; off >>= 1) {
                    ls[r] += __shfl_xor(ls[r], off, 64);
                    lq[r] += __shfl_xor(lq[r], off, 64);
                }
            if ((lane & 15) == 0)
#pragma unroll
                for (int r = 0; r < 4; ++r) {
                    sls[wc * 256 + wr * 128 + m * 16 + crow0 + r] = ls[r];
                    slq[wc * 256 + wr * 128 + m * 16 + crow0 + r] = lq[r];
                }
        }
        __syncthreads();
        if (wc == 0) {
#pragma unroll
            for (int rep = 0; rep < 2; ++rep) {
                int rowB = wr * 128 + rep * 64 + lane;
                float s4 = sls[rowB] + sls[256 + rowB] + sls[512 + rowB] + sls[768 + rowB];
                float q4 = slq[rowB] + slq[256 + rowB] + slq[512 + rowB] + slq[768 + rowB];
                long sidx = ((long)bz * 4 + bx) * 2048 + by * 256 + rowB;
                aux3[sidx] = s4;
                aux4[sidx] = q4;
            }
        }
        return;
    }

#pragma unroll
    for (int m = 0; m < 8; ++m) {
#pragma unroll
        for (int n = 0; n < 4; ++n) {
            long gn = n0 + n * 16 + ccol;
#pragma unroll
            for (int r = 0; r < 4; ++r) {
                long gm = m0 + m * 16 + crow0 + r;
                float v = acc[m][n][r];
                if (MODE == 2) {
                    ((unsigned short*)Cout)[gm * N + gn] = f2b(fmaxf(v + aux1[gn], 0.f));
                } else {  // MODE 3
                    long idx = gm * N + gn;
                    ((unsigned short*)Cout)[idx] =
                        f2b(v + aux1[gn] + b2f(((const unsigned short*)aux2)[idx]));
                }
            }
        }
    }
#undef STAGE_A
#undef STAGE_B
}

// ---------------- combine per-tile partial sums -> 1/L per row ----------------
__global__ void suminv_kernel(const float* __restrict__ stats, float* __restrict__ invL) {
    int i = blockIdx.x * 256 + threadIdx.x;  // 32768 = 16 * 2048
    int bz = i >> 11, row = i & 2047;
    long base = (long)bz * 8 * 2048 + row;
    float L = 0.f;
#pragma unroll
    for (int t = 0; t < 8; ++t) L += stats[base + t * 2048];
    invL[i] = 1.f / L;
}

// ---------------- LN1 apply with inline stats combine (bf16 in-place) ----------------
__global__ void ln_apply_kernel(unsigned short* __restrict__ X, const float* __restrict__ ss,
                                const float* __restrict__ sq, const float* __restrict__ gamma,
                                const float* __restrict__ beta) {
    __shared__ float mr[4];
    int tid = threadIdx.x;
    long rowbase = (long)blockIdx.x * 2;  // 2 rows / block
    if (tid < 2) {
        long row = rowbase + tid;
        int bz = (int)(row >> 11), lrow = (int)(row & 2047);
        long base = (long)bz * 4 * 2048 + lrow;
        float s = 0.f, q = 0.f;
#pragma unroll
        for (int t = 0; t < 4; ++t) { s += ss[base + t * 2048]; q += sq[base + t * 2048]; }
        float m = s * (1.f / 1024.f);
        float var = q * (1.f / 1024.f) - m * m;
        mr[tid * 2] = m;
        mr[tid * 2 + 1] = rsqrtf(var + LN_EPS);
    }
    __syncthreads();
    int sub = tid >> 7;
    float m = mr[sub * 2], r = mr[sub * 2 + 1];
    long i = rowbase * 1024 + (long)tid * 8;
    int col = (tid * 8) & 1023;
    u16x8 raw = *reinterpret_cast<const u16x8*>(X + i);
    float4 g0 = *reinterpret_cast<const float4*>(gamma + col);
    float4 g1 = *reinterpret_cast<const float4*>(gamma + col + 4);
    float4 b0 = *reinterpret_cast<const float4*>(beta + col);
    float4 b1 = *reinterpret_cast<const float4*>(beta + col + 4);
    u16x8 o;
    o[0] = f2b((b2f(raw[0]) - m) * r * g0.x + b0.x);
    o[1] = f2b((b2f(raw[1]) - m) * r * g0.y + b0.y);
    o[2] = f2b((b2f(raw[2]) - m) * r * g0.z + b0.z);
    o[3] = f2b((b2f(raw[3]) - m) * r * g0.w + b0.w);
    o[4] = f2b((b2f(raw[4]) - m) * r * g1.x + b1.x);
    o[5] = f2b((b2f(raw[5]) - m) * r * g1.y + b1.y);
    o[6] = f2b((b2f(raw[6]) - m) * r * g1.z + b1.z);
    o[7] = f2b((b2f(raw[7]) - m) * r * g1.w + b1.w);
    *reinterpret_cast<u16x8*>(X + i) = o;
}

// ---------------- final LayerNorm: bf16 rows in, fp32 out ----------------
__device__ inline float wave_sum(float v) {
#pragma unroll
    for (int off = 32; off > 0; off >>= 1) v += __shfl_xor(v, off, 64);
    return v;
}

__global__ void ln_final_kernel(const unsigned short* __restrict__ Yb,
                                const float* __restrict__ gamma, const float* __restrict__ beta,
                                float* __restrict__ out) {
    __shared__ float red[8];
    long row = blockIdx.x;
    const unsigned short* y = Yb + row * 1024;
    int tid = threadIdx.x;
    int wv = tid >> 6, ln = tid & 63;
    u16x4 raw = *reinterpret_cast<const u16x4*>(y + tid * 4);
    float v0 = b2f(raw[0]), v1 = b2f(raw[1]), v2 = b2f(raw[2]), v3 = b2f(raw[3]);
    float s = v0 + v1 + v2 + v3;
    float q = v0 * v0 + v1 * v1 + v2 * v2 + v3 * v3;
    s = wave_sum(s);
    q = wave_sum(q);
    if (ln == 0) { red[wv] = s; red[4 + wv] = q; }
    __syncthreads();
    s = red[0] + red[1] + red[2] + red[3];
    q = red[4] + red[5] + red[6] + red[7];
    float mu = s * (1.f / 1024.f);
    float var = q * (1.f / 1024.f) - mu * mu;
    float rsg = rsqrtf(var + LN_EPS);
    float4 g = *reinterpret_cast<const float4*>(gamma + tid * 4);
    float4 b = *reinterpret_cast<const float4*>(beta + tid * 4);
    float4 o;
    o.x = (v0 - mu) * rsg * g.x + b.x;
    o.y = (v1 - mu) * rsg * g.y + b.y;
    o.z = (v2 - mu) * rsg * g.z + b.z;
    o.w = (v3 - mu) * rsg * g.w + b.w;
    *reinterpret_cast<float4*>(out + row * 1024 + tid * 4) = o;
}

extern "C" void kernel_launch(void* const* d_in, const int* in_sizes, int n_in,
                              void* d_out, int out_size, void* d_ws, size_t ws_size,
                              hipStream_t stream) {
    const float* Q     = (const float*)d_in[0];
    const float* Kin   = (const float*)d_in[1];
    const float* V     = (const float*)d_in[2];
    const float* W1    = (const float*)d_in[3];
    const float* b1    = (const float*)d_in[4];
    const float* W2    = (const float*)d_in[5];
    const float* b2    = (const float*)d_in[6];
    const float* gamma = (const float*)d_in[7];
    const float* beta  = (const float*)d_in[8];
    float* out = (float*)d_out;

    const int Bq = 16, S = 2048, D = 1024;
    const long SD = (long)S * D;
    const long SS = (long)S * S;
    const long rows = (long)Bq * S;  // 32768

    const size_t NEED = 3 * (size_t)(Bq * SD * 2) + 2 * (size_t)D * D * 2 + (size_t)(Bq * SS * 2);
    if (ws_size < NEED) return;

    char* ws = (char*)d_ws;
    unsigned short* Qb  = (unsigned short*)ws; ws += Bq * SD * 2;
    unsigned short* Kb  = (unsigned short*)ws; ws += Bq * SD * 2;
    unsigned short* Vt  = (unsigned short*)ws; ws += Bq * SD * 2;
    unsigned short* W1b = (unsigned short*)ws; ws += (long)D * D * 2;
    unsigned short* W2b = (unsigned short*)ws; ws += (long)D * D * 2;
    unsigned short* Sb  = (unsigned short*)ws; ws += Bq * SS * 2;

    unsigned short* Xb = Qb;                   // PV overwrites Qb with X bf16 (same-thread RMW)
    unsigned short* H  = Kb;                   // Kb dead after QK^T
    unsigned short* Yb = (unsigned short*)Sb;  // scores dead after PV

    // scratch in W1b/W2b region (weights converted after LN1 apply)
    char* sc = (char*)W1b;
    float* stats   = (float*)sc;               // 1 MB  (QK^T partial sums)
    float* invL    = (float*)(sc + 0x100000);  // 128 KB
    float* stats_s = (float*)(sc + 0x140000);  // 512 KB (LN1 sum partials)
    float* stats_q = (float*)(sc + 0x1C0000);  // 512 KB (LN1 sumsq partials)

    const int DYN_LDS = 131072;
    (void)hipFuncSetAttribute(reinterpret_cast<const void*>(&gemm256<0>),
                              hipFuncAttributeMaxDynamicSharedMemorySize, DYN_LDS);
    (void)hipFuncSetAttribute(reinterpret_cast<const void*>(&gemm256<1>),
                              hipFuncAttributeMaxDynamicSharedMemorySize, DYN_LDS);
    (void)hipFuncSetAttribute(reinterpret_cast<const void*>(&gemm256<2>),
                              hipFuncAttributeMaxDynamicSharedMemorySize, DYN_LDS);
    (void)hipFuncSetAttribute(reinterpret_cast<const void*>(&gemm256<3>),
                              hipFuncAttributeMaxDynamicSharedMemorySize, DYN_LDS);

    const float scale = 1.0f / (sqrtf((float)D) + 1e-8f);
    const float rescale = sqrtf((float)D) + 1e-8f;

    cvt2_kernel<<<2048, 256, 0, stream>>>(Q, Qb, Bq * SD, scale, Kin, Kb, Bq * SD);
    transpose_kernel<<<dim3(S / 32, D / 32, Bq), 256, 0, stream>>>(V, Vt, S, D);

    // QK^T + exp + partial sums  (tX=8, tY=8, 16 bz -> 1024 blocks)
    gemm256<0><<<1024, 512, DYN_LDS, stream>>>(
        Qb, Kb, Sb, stats, nullptr, nullptr, nullptr, 8, 8, S, D, SD, SD, SS, 1.0f);
    suminv_kernel<<<128, 256, 0, stream>>>(stats, invL);

    // PV * invL + Q residual -> X bf16 (over Qb) + LN1 partials  (tX=4, tY=8 -> 512)
    gemm256<1><<<512, 512, DYN_LDS, stream>>>(
        Sb, Vt, Xb, (const float*)Qb, invL, stats_s, stats_q, 4, 8, D, S, SS, SD, SD, rescale);
    ln_apply_kernel<<<16384, 256, 0, stream>>>(Xb, stats_s, stats_q, gamma, beta);

    cvt2_kernel<<<512, 256, 0, stream>>>(W1, W1b, (long)D * D, 1.0f, W2, W2b, (long)D * D);

    // FFN  (tX=4, tY=128 -> 512 blocks each)
    gemm256<2><<<512, 512, DYN_LDS, stream>>>(
        Xb, W1b, H, b1, nullptr, nullptr, nullptr, 4, 128, D, D, 0, 0, 0, 1.0f);
    gemm256<3><<<512, 512, DYN_LDS, stream>>>(
        H, W2b, Yb, b2, (const float*)Xb, nullptr, nullptr, 4, 128, D, D, 0, 0, 0, 1.0f);
    ln_final_kernel<<<rows, 256, 0, stream>>>(Yb, gamma, beta, out);
}